// Round 9
// baseline (196.452 us; speedup 1.0000x reference)
//
#include <hip/hip_runtime.h>

#define EPS_ 1e-4f

typedef _Float16 f16;
typedef _Float16 f16x8 __attribute__((ext_vector_type(8)));
typedef _Float16 f16x2 __attribute__((ext_vector_type(2)));
typedef __fp16 h16x2 __attribute__((ext_vector_type(2)));
typedef float f32x4v __attribute__((ext_vector_type(4)));
typedef float f32x2v __attribute__((ext_vector_type(2)));
typedef unsigned int u32;

__device__ inline f32x4v mfma16(f16x8 a, f16x8 b, f32x4v c) {
    return __builtin_amdgcn_mfma_f32_16x16x32_f16(a, b, c, 0, 0, 0);
}
__device__ inline f16x2 pk2(float a, float b) {
    h16x2 r = __builtin_amdgcn_cvt_pkrtz(a, b);
    return __builtin_bit_cast(f16x2, r);
}
__device__ inline u32 bc32(f16x2 v) { return __builtin_bit_cast(u32, v); }

__device__ inline f16x8 zero8() {
    f16x8 r;
#pragma unroll
    for (int i = 0; i < 8; i++) r[i] = (f16)0.f;
    return r;
}

__device__ inline f16x8 cvt8x2(f32x2v a, f32x2v b, f32x2v c, f32x2v d) {
    f16x2 p0 = pk2(a.x, a.y), p1 = pk2(b.x, b.y), p2 = pk2(c.x, c.y), p3 = pk2(d.x, d.y);
    f16x8 r;
    r[0] = p0[0]; r[1] = p0[1]; r[2] = p1[0]; r[3] = p1[1];
    r[4] = p2[0]; r[5] = p2[1]; r[6] = p3[0]; r[7] = p3[1];
    return r;
}

// g==2 lanes' bf[1]: sse48,49, x0,x1, s, 0,0,0
__device__ inline f16x8 mkg2(f32x2v e, f32x2v xv, float sv) {
    f16x8 t = zero8();
    t[0] = (f16)e.x; t[1] = (f16)e.y;
    t[2] = (f16)xv.x; t[3] = (f16)xv.y;
    t[4] = (f16)sv;
    return t;
}

// ---------------------------------------------------------------------------
// Kernel 1: 8x8 average pool.  sdf (2,1024,1024) -> pooled (2,128,128)
// ---------------------------------------------------------------------------
__global__ void pool_kernel(const float* __restrict__ sdf, float* __restrict__ pooled) {
    int t = blockIdx.x * blockDim.x + threadIdx.x;
    int c = t >> 14;
    int rem = t & 16383;
    int R = rem >> 7;
    int C = rem & 127;
    const float* base = sdf + c * 1048576 + (R * 8) * 1024 + C * 8;
    float sum = 0.f;
#pragma unroll
    for (int r = 0; r < 8; r++) {
        const float4* p = (const float4*)(base + r * 1024);
        float4 a = p[0];
        float4 b = p[1];
        sum += a.x + a.y + a.z + a.w + b.x + b.y + b.z + b.w;
    }
    pooled[t] = sum * (1.f / 64.f);
}

// ---------------------------------------------------------------------------
// Kernel 2: 5x5 conv, 2->16 ch, pad 2. pooled (2,128,128) -> A [(y*128+x)*16+f]
// ---------------------------------------------------------------------------
__global__ void conv_kernel(const float* __restrict__ pooled,
                            const float* __restrict__ conv_w,
                            const float* __restrict__ conv_b,
                            float* __restrict__ A) {
    int t = blockIdx.x * blockDim.x + threadIdx.x;
    int y = t >> 7, x = t & 127;
    float acc[16];
#pragma unroll
    for (int f = 0; f < 16; f++) acc[f] = conv_b[f];
#pragma unroll
    for (int c = 0; c < 2; c++) {
#pragma unroll
        for (int ky = 0; ky < 5; ky++) {
            int yy = y + ky - 2;
            if (yy < 0 || yy > 127) continue;
#pragma unroll
            for (int kx = 0; kx < 5; kx++) {
                int xx = x + kx - 2;
                if (xx < 0 || xx > 127) continue;
                float v = pooled[c * 16384 + yy * 128 + xx];
                int wbase = c * 25 + ky * 5 + kx;
#pragma unroll
                for (int f = 0; f < 16; f++)
                    acc[f] = fmaf(v, conv_w[f * 50 + wbase], acc[f]);
            }
        }
    }
    float4* out4 = (float4*)(A + t * 16);
#pragma unroll
    for (int q = 0; q < 4; q++)
        out4[q] = make_float4(acc[4 * q], acc[4 * q + 1], acc[4 * q + 2], acc[4 * q + 3]);
}

// ---------------------------------------------------------------------------
// Feature (k) order for layer 1:
//   k 0..49 = sse[0..49]; k50,51 = x0,x1; k52 = s; k53..55 = 0;
//   k56..71 = interp ch 0..15; k72 = bias slot; k73..95 = 0
// Kernel 3: pack weights into per-lane MFMA A-fragments (f16).
// frag f: f<24 -> w1 (mf=f/3,kc=f%3); 24..55 -> w2; 56..79 -> w3
// A-frag: lane l holds W[out=16*mf+(l&15)][k=32*kc+8*(l>>4)+i], i=0..7
// ---------------------------------------------------------------------------
__global__ void pack_kernel(const float* __restrict__ w1, const float* __restrict__ b1,
                            const float* __restrict__ w2, const float* __restrict__ w3,
                            f16* __restrict__ frags) {
    int t = blockIdx.x * blockDim.x + threadIdx.x;
    if (t >= 80 * 64) return;
    int f = t >> 6, lane = t & 63;
    int g = lane >> 4, col = lane & 15;
    f16 v[8];
    if (f < 24) {
        int mf = f / 3, kc = f % 3;
        int o = mf * 16 + col;
#pragma unroll
        for (int i = 0; i < 8; i++) {
            int k = kc * 32 + g * 8 + i;
            float val = 0.f;
            if (k < 50) val = w1[(3 + k) * 128 + o];
            else if (k == 50) val = w1[0 * 128 + o];
            else if (k == 51) val = w1[1 * 128 + o];
            else if (k == 52) val = w1[2 * 128 + o];
            else if (k >= 56 && k < 72) val = w1[(53 + (k - 56)) * 128 + o];
            else if (k == 72) val = b1[o];
            v[i] = (f16)val;
        }
    } else if (f < 56) {
        int ff = f - 24, mf = ff >> 2, kc = ff & 3;
        int o = mf * 16 + col;
#pragma unroll
        for (int i = 0; i < 8; i++) {
            int k = kc * 32 + g * 8 + i;
            v[i] = (f16)w2[k * 128 + o];
        }
    } else {
        int ff = f - 56, mf = ff >> 2, kc = ff & 3;
        int o = mf * 16 + col;
#pragma unroll
        for (int i = 0; i < 8; i++) {
            int k = kc * 32 + g * 8 + i;
            v[i] = (f16)w3[k * 96 + o];
        }
    }
    f16* dst = frags + (f * 64 + lane) * 8;
#pragma unroll
    for (int i = 0; i < 8; i++) dst[i] = v[i];
}

// ---------------------------------------------------------------------------
// Kernel 4: fused interp + MLP.  768 threads = 12 waves, 1 block/CU,
// 3 waves/SIMD (cap 168 unified regs/wave; flat __launch_bounds__(768) only).
// Staged software pipeline: next-iter inputs are loaded/converted in phases
// placed where their registers die ->
//   iter top: issue c0/x/e/s loads      (latency hidden under L1)
//   post-L1 : cvt c0 -> bf0; issue c1   (c1 hidden under L2)
//   post-L2 : cvt c1 -> bf1
//   post-TRANS2: INTERP next tile       (gathers hidden under L3)
//   post-L3 : pull interp from LDS -> bf1(g3)/bf2(g0)
// Current-iter bf is consumed only by L1, so next-frag construction reuses
// the same registers.  Weight frags in LDS (80 KB shared); 32 pts/wave/iter.
// ---------------------------------------------------------------------------
__global__ void __launch_bounds__(768) mlp_kernel(
    const float* __restrict__ x, const float* __restrict__ s,
    const float* __restrict__ sse, const float* __restrict__ Amat,
    const float4* __restrict__ fragsv,
    const float* __restrict__ b2, const float* __restrict__ b3,
    const float* __restrict__ w4, const float* __restrict__ b4,
    float* __restrict__ out) {
    __shared__ f16 wlds[40960];        // 80 frags * 64 lanes * 8 f16 = 80 KB
    __shared__ f16 acth[12][2048];     // per-wave buffer: interp stage OR h transit
    __shared__ float bias2[128];
    __shared__ float bias3[96];
    __shared__ float w4l[96];

    const int tid = threadIdx.x;
    const int wv = tid >> 6;
    const int lane = tid & 63;
    const int g = lane >> 4, col = lane & 15;
    const int swz = (col & 7) << 3;    // f16-index swizzle bits 3..5

    {   // cooperative staging: 80KB frags + biases
        float4* wl4 = (float4*)wlds;
        for (int i = tid; i < 5120; i += 768) wl4[i] = fragsv[i];
        if (tid < 128) bias2[tid] = b2[tid];
        if (tid < 96) { bias3[tid] = b3[tid]; w4l[tid] = w4[tid]; }
    }
    __syncthreads();
    const float b4v = b4[0];

    f16* ah = acth[wv];
    u32* ibA = (u32*)ah;               // interp staging tile A: u32 [0,192)
    u32* ibB = (u32*)ah + 192;         // tile B: u32 [192,384)

    const int wtotal = 31250;          // 1e6 / 32
    int wg = blockIdx.x * 12 + wv;
    const int wstride = gridDim.x * 12;

    // pipeline registers (next-iter raw + current bf frags)
    f32x2v Ac0[4], Ac1[4], Ae, Axv; float Asv;
    f32x2v Bc0[4], Bc1[4], Be, Bxv; float Bsv;
    f16x8 bfA[3], bfB[3];

    auto ISSUE0 = [&](int pt0, f32x2v* c0, f32x2v& e, f32x2v& xv, float& sv) {
        const float* base = sse + (long)(pt0 + col) * 50;
#pragma unroll
        for (int q = 0; q < 4; q++) c0[q] = *(const f32x2v*)(base + 8 * g + 2 * q);
        if (g == 2) {
            e = *(const f32x2v*)(base + 48);
            sv = s[pt0 + col];
        }
        xv = *(const f32x2v*)(x + 2 * (pt0 + col));
    };
    auto ISSUE1 = [&](int pt0, f32x2v* c1) {
        if (g < 2) {
            const float* base = sse + (long)(pt0 + col) * 50;
#pragma unroll
            for (int q = 0; q < 4; q++) c1[q] = *(const f32x2v*)(base + 32 + 8 * g + 2 * q);
        }
    };

    // per-lane interp: pt=col, channels 4g..4g+3 -> ib u32 slots 2g,2g+1
    auto INTERP = [&](f32x2v xv, u32* ib) {
        float gx = fminf(fmaxf(xv.x, EPS_), 1.f - EPS_) * 127.f;
        float gy = fminf(fmaxf(xv.y, EPS_), 1.f - EPS_) * 127.f;
        float fx0 = floorf(gx), fy0 = floorf(gy);
        int ix0 = (int)fx0, iy0 = (int)fy0;
        int ix1 = min(ix0 + 1, 127), iy1 = min(iy0 + 1, 127);
        float wx = gx - fx0, wy = gy - fy0;
        const f32x4v* A4 = (const f32x4v*)Amat;
        f32x4v f00 = A4[(iy0 * 128 + ix0) * 4 + g];
        f32x4v f10 = A4[(iy0 * 128 + ix1) * 4 + g];
        f32x4v f01 = A4[(iy1 * 128 + ix0) * 4 + g];
        f32x4v f11 = A4[(iy1 * 128 + ix1) * 4 + g];
        float w00 = (1.f - wx) * (1.f - wy), w10 = wx * (1.f - wy);
        float w01 = (1.f - wx) * wy, w11 = wx * wy;
        f32x4v r = f00 * w00 + f10 * w10 + f01 * w01 + f11 * w11;
        uint2 uv;
        uv.x = bc32(pk2(r.x, r.y));
        uv.y = bc32(pk2(r.z, r.w));
        *(uint2*)(ib + col * 12 + 2 * g) = uv;
    };

    // C-layout (out=16mf+4g+r, pt=col) -> relu(+bias) -> ah -> B-frags of h
    auto TRANS = [&](f32x4v* acc, const float* bias, f16x8* hbf) {
#pragma unroll
        for (int mf = 0; mf < 8; mf++) {
            f32x4v v = acc[mf];
            if (bias) {
                f32x4v bb = *(const f32x4v*)&bias[mf * 16 + g * 4];
                v = v + bb;
            }
            uint2 uv;
            uv.x = bc32(pk2(fmaxf(v.x, 0.f), fmaxf(v.y, 0.f)));
            uv.y = bc32(pk2(fmaxf(v.z, 0.f), fmaxf(v.w, 0.f)));
            *(uint2*)&ah[(col * 128 + mf * 16 + g * 4) ^ swz] = uv;
        }
#pragma unroll
        for (int kc = 0; kc < 4; kc++)
            hbf[kc] = *(const f16x8*)&ah[(col * 128 + kc * 32 + g * 8) ^ swz];
    };

    auto L4OUT = [&](f32x4v* acc3, int pt0) {
        float partial = 0.f;
#pragma unroll
        for (int mf = 0; mf < 6; mf++) {
            f32x4v bb = *(const f32x4v*)&bias3[mf * 16 + g * 4];
            f32x4v wv4 = *(const f32x4v*)&w4l[mf * 16 + g * 4];
            partial += fmaxf(acc3[mf].x + bb.x, 0.f) * wv4.x;
            partial += fmaxf(acc3[mf].y + bb.y, 0.f) * wv4.y;
            partial += fmaxf(acc3[mf].z + bb.z, 0.f) * wv4.z;
            partial += fmaxf(acc3[mf].w + bb.w, 0.f) * wv4.w;
        }
        partial += __shfl_xor(partial, 16);
        partial += __shfl_xor(partial, 32);
        if (g == 0) out[pt0 + col] = partial + b4v;
    };

    // ---- prologue: build bf for the first iteration (one-time stalls) ----
    if (wg < wtotal) {
        ISSUE0(wg * 32, Ac0, Ae, Axv, Asv);
        ISSUE0(wg * 32 + 16, Bc0, Be, Bxv, Bsv);
        ISSUE1(wg * 32, Ac1);
        ISSUE1(wg * 32 + 16, Bc1);
        INTERP(Axv, ibA);
        INTERP(Bxv, ibB);
        bfA[0] = cvt8x2(Ac0[0], Ac0[1], Ac0[2], Ac0[3]);
        bfB[0] = cvt8x2(Bc0[0], Bc0[1], Bc0[2], Bc0[3]);
        if (g < 2) {
            bfA[1] = cvt8x2(Ac1[0], Ac1[1], Ac1[2], Ac1[3]);
            bfB[1] = cvt8x2(Bc1[0], Bc1[1], Bc1[2], Bc1[3]);
        } else if (g == 2) {
            bfA[1] = mkg2(Ae, Axv, Asv);
            bfB[1] = mkg2(Be, Bxv, Bsv);
        } else {
            bfA[1] = *(const f16x8*)(ibA + col * 12);
            bfB[1] = *(const f16x8*)(ibB + col * 12);
        }
        if (g == 0) {
            bfA[2] = *(const f16x8*)(ibA + col * 12 + 4);
            bfB[2] = *(const f16x8*)(ibB + col * 12 + 4);
        } else if (g == 1) {
            f16x8 t = zero8();
            t[0] = (f16)1.f;                 // k=72 bias slot
            bfA[2] = t; bfB[2] = t;
        } else {
            bfA[2] = zero8(); bfB[2] = zero8();
        }
    }

    for (; wg < wtotal; wg += wstride) {
        const int pt0 = wg * 32;
        const int wgn = wg + wstride;
        const bool more = (wgn < wtotal);

        // ---- stage 0: issue next c0/e/x/s (hidden under L1) ----
        if (more) {
            ISSUE0(wgn * 32, Ac0, Ae, Axv, Asv);
            ISSUE0(wgn * 32 + 16, Bc0, Be, Bxv, Bsv);
        }

        // ---- Layer 1: K=96 (3 kc), 8 mf ----
        f32x4v accA[8], accB[8];
#pragma unroll
        for (int mf = 0; mf < 8; mf++) {
            accA[mf] = (f32x4v)(0.f);
            accB[mf] = (f32x4v)(0.f);
        }
#pragma unroll
        for (int kc = 0; kc < 3; kc++) {
#pragma unroll
            for (int mf = 0; mf < 8; mf++) {
                f16x8 wf = *(const f16x8*)&wlds[((mf * 3 + kc) * 64 + lane) * 8];
                accA[mf] = mfma16(wf, bfA[kc], accA[mf]);
                accB[mf] = mfma16(wf, bfB[kc], accB[mf]);
            }
        }

        // ---- stage 1: cvt c0 -> next bf0 (+g2 bf1); issue c1 (hidden under L2) ----
        if (more) {
            bfA[0] = cvt8x2(Ac0[0], Ac0[1], Ac0[2], Ac0[3]);
            bfB[0] = cvt8x2(Bc0[0], Bc0[1], Bc0[2], Bc0[3]);
            if (g == 2) {
                bfA[1] = mkg2(Ae, Axv, Asv);
                bfB[1] = mkg2(Be, Bxv, Bsv);
            }
            ISSUE1(wgn * 32, Ac1);
            ISSUE1(wgn * 32 + 16, Bc1);
        }

        f16x8 hbfA[4], hbfB[4];
        TRANS(accA, nullptr, hbfA);   // L1 bias came via k=72 slot
        TRANS(accB, nullptr, hbfB);

        // ---- Layer 2: K=128 (4 kc), 8 mf ----
        f32x4v acc2A[8], acc2B[8];
#pragma unroll
        for (int mf = 0; mf < 8; mf++) {
            acc2A[mf] = (f32x4v)(0.f);
            acc2B[mf] = (f32x4v)(0.f);
        }
#pragma unroll
        for (int kc = 0; kc < 4; kc++) {
#pragma unroll
            for (int mf = 0; mf < 8; mf++) {
                f16x8 wf = *(const f16x8*)&wlds[((24 + mf * 4 + kc) * 64 + lane) * 8];
                acc2A[mf] = mfma16(wf, hbfA[kc], acc2A[mf]);
                acc2B[mf] = mfma16(wf, hbfB[kc], acc2B[mf]);
            }
        }

        // ---- stage 2: cvt c1 -> next bf1 (g<2; reg-only) ----
        if (more && g < 2) {
            bfA[1] = cvt8x2(Ac1[0], Ac1[1], Ac1[2], Ac1[3]);
            bfB[1] = cvt8x2(Bc1[0], Bc1[1], Bc1[2], Bc1[3]);
        }

        TRANS(acc2A, bias2, hbfA);
        TRANS(acc2B, bias2, hbfB);

        // ---- stage 3: interp for next iter (ah free after TRANS2 reads;
        //      gathers hidden under L3) ----
        if (more) {
            INTERP(Axv, ibA);
            INTERP(Bxv, ibB);
        }

        // ---- Layer 3: K=128 (4 kc), 6 mf ----
        f32x4v acc3A[6], acc3B[6];
#pragma unroll
        for (int mf = 0; mf < 6; mf++) {
            acc3A[mf] = (f32x4v)(0.f);
            acc3B[mf] = (f32x4v)(0.f);
        }
#pragma unroll
        for (int kc = 0; kc < 4; kc++) {
#pragma unroll
            for (int mf = 0; mf < 6; mf++) {
                f16x8 wf = *(const f16x8*)&wlds[((56 + mf * 4 + kc) * 64 + lane) * 8];
                acc3A[mf] = mfma16(wf, hbfA[kc], acc3A[mf]);
                acc3B[mf] = mfma16(wf, hbfB[kc], acc3B[mf]);
            }
        }

        // ---- stage 4: pull interp results -> next bf1(g3)/bf2(g0) ----
        if (more) {
            if (g == 3) {
                bfA[1] = *(const f16x8*)(ibA + col * 12);
                bfB[1] = *(const f16x8*)(ibB + col * 12);
            }
            if (g == 0) {
                bfA[2] = *(const f16x8*)(ibA + col * 12 + 4);
                bfB[2] = *(const f16x8*)(ibB + col * 12 + 4);
            }
        }

        // ---- Layer 4 + output ----
        L4OUT(acc3A, pt0);
        L4OUT(acc3B, pt0 + 16);
    }
}

// ---------------------------------------------------------------------------
extern "C" void kernel_launch(void* const* d_in, const int* in_sizes, int n_in,
                              void* d_out, int out_size, void* d_ws, size_t ws_size,
                              hipStream_t stream) {
    const float* x      = (const float*)d_in[0];
    const float* s      = (const float*)d_in[1];
    const float* sse    = (const float*)d_in[2];
    const float* sdf    = (const float*)d_in[3];
    const float* conv_w = (const float*)d_in[4];
    const float* conv_b = (const float*)d_in[5];
    const float* w1     = (const float*)d_in[6];
    const float* b1     = (const float*)d_in[7];
    const float* w2     = (const float*)d_in[8];
    const float* b2     = (const float*)d_in[9];
    const float* w3     = (const float*)d_in[10];
    const float* b3     = (const float*)d_in[11];
    const float* w4     = (const float*)d_in[12];
    const float* b4     = (const float*)d_in[13];
    float* out = (float*)d_out;

    float* pooled = (float*)d_ws;            // 32768 f32  [0, 131072) bytes
    float* A      = pooled + 32768;          // 262144 f32 [131072, 1179648)
    f16*   frags  = (f16*)d_ws;              // 80 KB, reuses pooled region
                                             // (written by pack AFTER conv reads pooled)

    pool_kernel<<<128, 256, 0, stream>>>(sdf, pooled);
    conv_kernel<<<64, 256, 0, stream>>>(pooled, conv_w, conv_b, A);
    pack_kernel<<<20, 256, 0, stream>>>(w1, b1, w2, w3, frags);
    mlp_kernel<<<256, 768, 0, stream>>>(x, s, sse, A, (const float4*)frags,
                                        b2, b3, w4, b4, out);
}

// Round 10
// 188.848 us; speedup vs baseline: 1.0403x; 1.0403x over previous
//
#include <hip/hip_runtime.h>

#define EPS_ 1e-4f

typedef _Float16 f16;
typedef _Float16 f16x8 __attribute__((ext_vector_type(8)));
typedef _Float16 f16x2 __attribute__((ext_vector_type(2)));
typedef __fp16 h16x2 __attribute__((ext_vector_type(2)));
typedef float f32x4v __attribute__((ext_vector_type(4)));
typedef float f32x2v __attribute__((ext_vector_type(2)));
typedef unsigned int u32;

__device__ inline f32x4v mfma16(f16x8 a, f16x8 b, f32x4v c) {
    return __builtin_amdgcn_mfma_f32_16x16x32_f16(a, b, c, 0, 0, 0);
}
__device__ inline f16x2 pk2(float a, float b) {
    h16x2 r = __builtin_amdgcn_cvt_pkrtz(a, b);
    return __builtin_bit_cast(f16x2, r);
}
__device__ inline u32 bc32(f16x2 v) { return __builtin_bit_cast(u32, v); }

__device__ inline f16x8 zero8() {
    f16x8 r;
#pragma unroll
    for (int i = 0; i < 8; i++) r[i] = (f16)0.f;
    return r;
}

__device__ inline f16x8 cvt8x2(f32x2v a, f32x2v b, f32x2v c, f32x2v d) {
    f16x2 p0 = pk2(a.x, a.y), p1 = pk2(b.x, b.y), p2 = pk2(c.x, c.y), p3 = pk2(d.x, d.y);
    f16x8 r;
    r[0] = p0[0]; r[1] = p0[1]; r[2] = p1[0]; r[3] = p1[1];
    r[4] = p2[0]; r[5] = p2[1]; r[6] = p3[0]; r[7] = p3[1];
    return r;
}

// ---------------------------------------------------------------------------
// Kernel 1: 8x8 average pool.  sdf (2,1024,1024) -> pooled (2,128,128)
// ---------------------------------------------------------------------------
__global__ void pool_kernel(const float* __restrict__ sdf, float* __restrict__ pooled) {
    int t = blockIdx.x * blockDim.x + threadIdx.x;
    int c = t >> 14;
    int rem = t & 16383;
    int R = rem >> 7;
    int C = rem & 127;
    const float* base = sdf + c * 1048576 + (R * 8) * 1024 + C * 8;
    float sum = 0.f;
#pragma unroll
    for (int r = 0; r < 8; r++) {
        const float4* p = (const float4*)(base + r * 1024);
        float4 a = p[0];
        float4 b = p[1];
        sum += a.x + a.y + a.z + a.w + b.x + b.y + b.z + b.w;
    }
    pooled[t] = sum * (1.f / 64.f);
}

// ---------------------------------------------------------------------------
// Kernel 2: 5x5 conv, 2->16 ch, pad 2. pooled (2,128,128) -> A [(y*128+x)*16+f]
// ---------------------------------------------------------------------------
__global__ void conv_kernel(const float* __restrict__ pooled,
                            const float* __restrict__ conv_w,
                            const float* __restrict__ conv_b,
                            float* __restrict__ A) {
    int t = blockIdx.x * blockDim.x + threadIdx.x;
    int y = t >> 7, x = t & 127;
    float acc[16];
#pragma unroll
    for (int f = 0; f < 16; f++) acc[f] = conv_b[f];
#pragma unroll
    for (int c = 0; c < 2; c++) {
#pragma unroll
        for (int ky = 0; ky < 5; ky++) {
            int yy = y + ky - 2;
            if (yy < 0 || yy > 127) continue;
#pragma unroll
            for (int kx = 0; kx < 5; kx++) {
                int xx = x + kx - 2;
                if (xx < 0 || xx > 127) continue;
                float v = pooled[c * 16384 + yy * 128 + xx];
                int wbase = c * 25 + ky * 5 + kx;
#pragma unroll
                for (int f = 0; f < 16; f++)
                    acc[f] = fmaf(v, conv_w[f * 50 + wbase], acc[f]);
            }
        }
    }
    float4* out4 = (float4*)(A + t * 16);
#pragma unroll
    for (int q = 0; q < 4; q++)
        out4[q] = make_float4(acc[4 * q], acc[4 * q + 1], acc[4 * q + 2], acc[4 * q + 3]);
}

// ---------------------------------------------------------------------------
// Feature (k) order for layer 1:
//   k 0..49 = sse[0..49]; k50,51 = x0,x1; k52 = s; k53..55 = 0;
//   k56..71 = interp ch 0..15; k72 = bias slot; k73..95 = 0
// Kernel 3: pack weights into per-lane MFMA A-fragments (f16).
// frag f: f<24 -> w1 (mf=f/3,kc=f%3); 24..55 -> w2; 56..79 -> w3
// A-frag: lane l holds W[out=16*mf+(l&15)][k=32*kc+8*(l>>4)+i], i=0..7
// ---------------------------------------------------------------------------
__global__ void pack_kernel(const float* __restrict__ w1, const float* __restrict__ b1,
                            const float* __restrict__ w2, const float* __restrict__ w3,
                            f16* __restrict__ frags) {
    int t = blockIdx.x * blockDim.x + threadIdx.x;
    if (t >= 80 * 64) return;
    int f = t >> 6, lane = t & 63;
    int g = lane >> 4, col = lane & 15;
    f16 v[8];
    if (f < 24) {
        int mf = f / 3, kc = f % 3;
        int o = mf * 16 + col;
#pragma unroll
        for (int i = 0; i < 8; i++) {
            int k = kc * 32 + g * 8 + i;
            float val = 0.f;
            if (k < 50) val = w1[(3 + k) * 128 + o];
            else if (k == 50) val = w1[0 * 128 + o];
            else if (k == 51) val = w1[1 * 128 + o];
            else if (k == 52) val = w1[2 * 128 + o];
            else if (k >= 56 && k < 72) val = w1[(53 + (k - 56)) * 128 + o];
            else if (k == 72) val = b1[o];
            v[i] = (f16)val;
        }
    } else if (f < 56) {
        int ff = f - 24, mf = ff >> 2, kc = ff & 3;
        int o = mf * 16 + col;
#pragma unroll
        for (int i = 0; i < 8; i++) {
            int k = kc * 32 + g * 8 + i;
            v[i] = (f16)w2[k * 128 + o];
        }
    } else {
        int ff = f - 56, mf = ff >> 2, kc = ff & 3;
        int o = mf * 16 + col;
#pragma unroll
        for (int i = 0; i < 8; i++) {
            int k = kc * 32 + g * 8 + i;
            v[i] = (f16)w3[k * 96 + o];
        }
    }
    f16* dst = frags + (f * 64 + lane) * 8;
#pragma unroll
    for (int i = 0; i < 8; i++) dst[i] = v[i];
}

// ---------------------------------------------------------------------------
// Kernel 4: fused interp + MLP.  512 threads = 8 waves, 1 block/CU
// (__launch_bounds__(512,1): 8 waves/CU -> 256-unified-reg cap; the r5
// failure was the (512,2) 128-cap + cross-iter prefetch, not the 4-tile
// structure).  Each wave: 64 pts/iter (4 tiles of 16) -> one 80-KB weight
// pass serves 4 B-tiles (2.5->1.25 KB LDS weight traffic per point).  No
// cross-iter sse prefetch: all raw loads issued at iter top (HBM latency
// hidden under INTERP's L2-resident gathers + 2-waves/SIMD TLP); only the
// 8-reg coordinate prefetch crosses iterations.  Per-wave 4-KB buffer =
// interp staging (3 KB as 4x192 u32) OR transition buffer (phases disjoint).
// ---------------------------------------------------------------------------
__global__ void __launch_bounds__(512, 1) mlp_kernel(
    const float* __restrict__ x, const float* __restrict__ s,
    const float* __restrict__ sse, const float* __restrict__ Amat,
    const float4* __restrict__ fragsv,
    const float* __restrict__ b2, const float* __restrict__ b3,
    const float* __restrict__ w4, const float* __restrict__ b4,
    float* __restrict__ out) {
    __shared__ f16 wlds[40960];        // 80 frags * 64 lanes * 8 f16 = 80 KB
    __shared__ f16 acth[8][2048];      // per-wave buffer: interp stage OR h transit
    __shared__ float bias2[128];
    __shared__ float bias3[96];
    __shared__ float w4l[96];

    const int tid = threadIdx.x;
    const int wv = tid >> 6;
    const int lane = tid & 63;
    const int g = lane >> 4, col = lane & 15;
    const int swz = (col & 7) << 3;    // f16-index swizzle bits 3..5

    {   // cooperative staging: 80KB frags + biases
        float4* wl4 = (float4*)wlds;
        for (int i = tid; i < 5120; i += 512) wl4[i] = fragsv[i];
        if (tid < 128) bias2[tid] = b2[tid];
        if (tid < 96) { bias3[tid] = b3[tid]; w4l[tid] = w4[tid]; }
    }
    __syncthreads();
    const float b4v = b4[0];

    f16* ah = acth[wv];

    const int wtotal = 15625;          // 1e6 / 64
    int wg = blockIdx.x * 8 + wv;
    const int wstride = gridDim.x * 8;

    f32x2v xv4[4];                     // coordinate prefetch only (8 regs)

    // per-lane interp: pt=col, channels 4g..4g+3 -> ib u32 slots 2g,2g+1
    auto INTERP = [&](f32x2v xv, u32* ib) {
        float gx = fminf(fmaxf(xv.x, EPS_), 1.f - EPS_) * 127.f;
        float gy = fminf(fmaxf(xv.y, EPS_), 1.f - EPS_) * 127.f;
        float fx0 = floorf(gx), fy0 = floorf(gy);
        int ix0 = (int)fx0, iy0 = (int)fy0;
        int ix1 = min(ix0 + 1, 127), iy1 = min(iy0 + 1, 127);
        float wx = gx - fx0, wy = gy - fy0;
        const f32x4v* A4 = (const f32x4v*)Amat;
        f32x4v f00 = A4[(iy0 * 128 + ix0) * 4 + g];
        f32x4v f10 = A4[(iy0 * 128 + ix1) * 4 + g];
        f32x4v f01 = A4[(iy1 * 128 + ix0) * 4 + g];
        f32x4v f11 = A4[(iy1 * 128 + ix1) * 4 + g];
        float w00 = (1.f - wx) * (1.f - wy), w10 = wx * (1.f - wy);
        float w01 = (1.f - wx) * wy, w11 = wx * wy;
        f32x4v r = f00 * w00 + f10 * w10 + f01 * w01 + f11 * w11;
        uint2 uv;
        uv.x = bc32(pk2(r.x, r.y));
        uv.y = bc32(pk2(r.z, r.w));
        *(uint2*)(ib + col * 12 + 2 * g) = uv;
    };

    // C-layout (out=16mf+4g+r, pt=col) -> relu(+bias) -> ah -> B-frags of h
    auto TRANS = [&](f32x4v* acc, const float* bias, f16x8* hbf) {
#pragma unroll
        for (int mf = 0; mf < 8; mf++) {
            f32x4v v = acc[mf];
            if (bias) {
                f32x4v bb = *(const f32x4v*)&bias[mf * 16 + g * 4];
                v = v + bb;
            }
            uint2 uv;
            uv.x = bc32(pk2(fmaxf(v.x, 0.f), fmaxf(v.y, 0.f)));
            uv.y = bc32(pk2(fmaxf(v.z, 0.f), fmaxf(v.w, 0.f)));
            *(uint2*)&ah[(col * 128 + mf * 16 + g * 4) ^ swz] = uv;
        }
#pragma unroll
        for (int kc = 0; kc < 4; kc++)
            hbf[kc] = *(const f16x8*)&ah[(col * 128 + kc * 32 + g * 8) ^ swz];
    };

    auto L4OUT = [&](f32x4v* acc3, int pt0) {
        float partial = 0.f;
#pragma unroll
        for (int mf = 0; mf < 6; mf++) {
            f32x4v bb = *(const f32x4v*)&bias3[mf * 16 + g * 4];
            f32x4v wv4 = *(const f32x4v*)&w4l[mf * 16 + g * 4];
            partial += fmaxf(acc3[mf].x + bb.x, 0.f) * wv4.x;
            partial += fmaxf(acc3[mf].y + bb.y, 0.f) * wv4.y;
            partial += fmaxf(acc3[mf].z + bb.z, 0.f) * wv4.z;
            partial += fmaxf(acc3[mf].w + bb.w, 0.f) * wv4.w;
        }
        partial += __shfl_xor(partial, 16);
        partial += __shfl_xor(partial, 32);
        if (g == 0) out[pt0 + col] = partial + b4v;
    };

    if (wg < wtotal) {
#pragma unroll
        for (int t = 0; t < 4; t++)
            xv4[t] = *(const f32x2v*)(x + 2 * (wg * 64 + 16 * t + col));
    }

    for (; wg < wtotal; wg += wstride) {
        const int pt0 = wg * 64;

        // ---- phase 1: issue ALL raw loads (HBM latency starts now) ----
        f32x2v c0[4][4], c1[4][4], e4[4];
        float sv4[4];
#pragma unroll
        for (int t = 0; t < 4; t++) {
            const float* base = sse + (long)(pt0 + 16 * t + col) * 50;
#pragma unroll
            for (int q = 0; q < 4; q++) c0[t][q] = *(const f32x2v*)(base + 8 * g + 2 * q);
            if (g < 2) {
#pragma unroll
                for (int q = 0; q < 4; q++) c1[t][q] = *(const f32x2v*)(base + 32 + 8 * g + 2 * q);
            } else if (g == 2) {
                e4[t] = *(const f32x2v*)(base + 48);
                sv4[t] = s[pt0 + 16 * t + col];
            }
        }

        // ---- phase 2: interp (L2-resident gathers + VALU hide HBM) ----
#pragma unroll
        for (int t = 0; t < 4; t++) INTERP(xv4[t], (u32*)ah + 192 * t);

        // ---- phase 3: build B-frags (consume raws; read interp buffer) ----
        f16x8 bf[4][3];
#pragma unroll
        for (int t = 0; t < 4; t++) {
            const u32* ib = (const u32*)ah + 192 * t;
            bf[t][0] = cvt8x2(c0[t][0], c0[t][1], c0[t][2], c0[t][3]);
            if (g < 2) {
                bf[t][1] = cvt8x2(c1[t][0], c1[t][1], c1[t][2], c1[t][3]);
            } else if (g == 2) {
                f16x8 tt = zero8();
                tt[0] = (f16)e4[t].x; tt[1] = (f16)e4[t].y;     // sse 48,49
                tt[2] = (f16)xv4[t].x; tt[3] = (f16)xv4[t].y;   // x0,x1
                tt[4] = (f16)sv4[t];                            // s
                bf[t][1] = tt;
            } else {
                bf[t][1] = *(const f16x8*)(ib + col * 12);      // interp ch 0..7
            }
            if (g == 0) {
                bf[t][2] = *(const f16x8*)(ib + col * 12 + 4);  // interp ch 8..15
            } else if (g == 1) {
                f16x8 tt = zero8();
                tt[0] = (f16)1.f;                               // k=72 bias slot
                bf[t][2] = tt;
            } else {
                bf[t][2] = zero8();
            }
        }

        // ---- prefetch next coords (raw regs now dead) ----
        int wgn = wg + wstride;
        if (wgn < wtotal) {
#pragma unroll
            for (int t = 0; t < 4; t++)
                xv4[t] = *(const f32x2v*)(x + 2 * (wgn * 64 + 16 * t + col));
        }

        // ---- Layer 1: K=96 (3 kc), 8 mf, 4 tiles ----
        f32x4v acc1[4][8];
#pragma unroll
        for (int t = 0; t < 4; t++)
#pragma unroll
            for (int mf = 0; mf < 8; mf++) acc1[t][mf] = (f32x4v)(0.f);
#pragma unroll
        for (int kc = 0; kc < 3; kc++) {
#pragma unroll
            for (int mf = 0; mf < 8; mf++) {
                f16x8 wf = *(const f16x8*)&wlds[((mf * 3 + kc) * 64 + lane) * 8];
#pragma unroll
                for (int t = 0; t < 4; t++)
                    acc1[t][mf] = mfma16(wf, bf[t][kc], acc1[t][mf]);
            }
        }

        // ---- transition 1 (tile-serial through the 4-KB buffer) ----
        f16x8 hbf[4][4];
#pragma unroll
        for (int t = 0; t < 4; t++) TRANS(acc1[t], nullptr, hbf[t]);

        // ---- Layer 2: K=128 (4 kc), 8 mf, 4 tiles ----
        f32x4v acc2[4][8];
#pragma unroll
        for (int t = 0; t < 4; t++)
#pragma unroll
            for (int mf = 0; mf < 8; mf++) acc2[t][mf] = (f32x4v)(0.f);
#pragma unroll
        for (int kc = 0; kc < 4; kc++) {
#pragma unroll
            for (int mf = 0; mf < 8; mf++) {
                f16x8 wf = *(const f16x8*)&wlds[((24 + mf * 4 + kc) * 64 + lane) * 8];
#pragma unroll
                for (int t = 0; t < 4; t++)
                    acc2[t][mf] = mfma16(wf, hbf[t][kc], acc2[t][mf]);
            }
        }

        // ---- transition 2 ----
#pragma unroll
        for (int t = 0; t < 4; t++) TRANS(acc2[t], bias2, hbf[t]);

        // ---- Layer 3: K=128 (4 kc), 6 mf, 4 tiles ----
        f32x4v acc3[4][6];
#pragma unroll
        for (int t = 0; t < 4; t++)
#pragma unroll
            for (int mf = 0; mf < 6; mf++) acc3[t][mf] = (f32x4v)(0.f);
#pragma unroll
        for (int kc = 0; kc < 4; kc++) {
#pragma unroll
            for (int mf = 0; mf < 6; mf++) {
                f16x8 wf = *(const f16x8*)&wlds[((56 + mf * 4 + kc) * 64 + lane) * 8];
#pragma unroll
                for (int t = 0; t < 4; t++)
                    acc3[t][mf] = mfma16(wf, hbf[t][kc], acc3[t][mf]);
            }
        }

        // ---- Layer 4 + output ----
#pragma unroll
        for (int t = 0; t < 4; t++) L4OUT(acc3[t], pt0 + 16 * t);
    }
}

// ---------------------------------------------------------------------------
extern "C" void kernel_launch(void* const* d_in, const int* in_sizes, int n_in,
                              void* d_out, int out_size, void* d_ws, size_t ws_size,
                              hipStream_t stream) {
    const float* x      = (const float*)d_in[0];
    const float* s      = (const float*)d_in[1];
    const float* sse    = (const float*)d_in[2];
    const float* sdf    = (const float*)d_in[3];
    const float* conv_w = (const float*)d_in[4];
    const float* conv_b = (const float*)d_in[5];
    const float* w1     = (const float*)d_in[6];
    const float* b1     = (const float*)d_in[7];
    const float* w2     = (const float*)d_in[8];
    const float* b2     = (const float*)d_in[9];
    const float* w3     = (const float*)d_in[10];
    const float* b3     = (const float*)d_in[11];
    const float* w4     = (const float*)d_in[12];
    const float* b4     = (const float*)d_in[13];
    float* out = (float*)d_out;

    float* pooled = (float*)d_ws;            // 32768 f32  [0, 131072) bytes
    float* A      = pooled + 32768;          // 262144 f32 [131072, 1179648)
    f16*   frags  = (f16*)d_ws;              // 80 KB, reuses pooled region
                                             // (written by pack AFTER conv reads pooled)

    pool_kernel<<<128, 256, 0, stream>>>(sdf, pooled);
    conv_kernel<<<64, 256, 0, stream>>>(pooled, conv_w, conv_b, A);
    pack_kernel<<<20, 256, 0, stream>>>(w1, b1, w2, w3, frags);
    mlp_kernel<<<256, 512, 0, stream>>>(x, s, sse, A, (const float4*)frags,
                                        b2, b3, w4, b4, out);
}